// Round 1
// 1934.555 us; speedup vs baseline: 1.0911x; 1.0911x over previous
//
#include <hip/hip_runtime.h>
#include <hip/hip_bf16.h>
#include <math.h>

#define NTOK 49
#define CDIM 192
#define NH   6
#define HD   32
#define XSTR 200   // bf16 row stride for xoh / ap (49-row tiles)
#define QSTR 40    // q/k per-head row stride
#define VSTR 72    // vt row stride (32 rows x 64 tokens padded)
#define PSTR 72    // p row stride

typedef short bf16x8 __attribute__((ext_vector_type(8)));
typedef float f32x4  __attribute__((ext_vector_type(4)));

__device__ __forceinline__ float bfu2f(unsigned short u) {
    return __uint_as_float(((unsigned int)u) << 16);
}
__device__ __forceinline__ short f2bf(float f) {
    union { __hip_bfloat16 h; short s; } cv; cv.h = __float2bfloat16(f); return cv.s;
}

// ---------------- weight fp32 -> bf16 prep (runs every launch; d_ws re-poisoned) ----
// segments (elems): wqkv 110592 | wproj 36864 | wf1 147456 | wf2 147456  = 442368
__global__ void conv_weights(const float* __restrict__ wqkv, const float* __restrict__ wpr,
                             const float* __restrict__ wf1,  const float* __restrict__ wf2,
                             unsigned short* __restrict__ ws) {
    int i = blockIdx.x * 256 + threadIdx.x;   // vec4 index, grid covers 110592 exactly
    int e = i * 4;
    const float* src;
    if      (e < 110592) src = wqkv + e;
    else if (e < 147456) src = wpr + (e - 110592);
    else if (e < 294912) src = wf1 + (e - 147456);
    else                 src = wf2 + (e - 294912);
    float4 v = *(const float4*)src;
    ushort4 o;
    o.x = (unsigned short)f2bf(v.x); o.y = (unsigned short)f2bf(v.y);
    o.z = (unsigned short)f2bf(v.z); o.w = (unsigned short)f2bf(v.w);
    *(ushort4*)(ws + e) = o;
}

// ---------------- fused swin block, MFMA everywhere -------------------------------
// LDS budget: xoh 49x200x2 = 19600 B, scr 19600 B, mask 512 B  => 39712 B
// -> 4 blocks/CU (was 75776 B -> 2 blocks/CU). All row reads for A-fragments are
// clamped to row 48; garbage rows only feed output rows discarded by r<NTOK guards.
__global__ __launch_bounds__(256, 4)
void swin_mfma_kernel(const float* __restrict__ x, const int* __restrict__ amask,
                      const float* __restrict__ g1, const float* __restrict__ b1,
                      const float* __restrict__ bqkv, const float* __restrict__ bpr,
                      const float* __restrict__ g2, const float* __restrict__ b2,
                      const float* __restrict__ bf1, const float* __restrict__ bf2,
                      const unsigned short* __restrict__ wbf,
                      float* __restrict__ out)
{
    __shared__ __align__(16) short lds[9800 + 9800];
    __shared__ unsigned long long smask_s[64];

    short* xoh = lds;              // 49x200: xn1 -> attn O -> xn2 -> hm chunk
    short* scr = lds + 9800;       // attention scratch, then ap (proj out)
    short* q_s  = scr;             // 49x40  (1960 shorts)
    short* k_s  = scr + 1960;      // 49x40  (1960 shorts)
    short* vt_s = scr + 3920;      // 32x72  (2304 shorts)
    short* p_s  = scr + 6224;      // 49x72  (3528 shorts; ends 9752 <= 9800)
    short* ap_s = scr;             // 49x200 bf16, lives after attention

    const int b    = blockIdx.x;
    const int tid  = threadIdx.x;
    const int lane = tid & 63;
    const int w    = tid >> 6;            // wave id = row-tile id
    const int l15  = lane & 15;
    const int quad = lane >> 4;
    const int rbase = 16 * w;
    const int arow  = rbase + l15;        // A-fragment row for this lane
    const int arow_c = (arow < NTOK) ? arow : (NTOK - 1);   // clamped (rows>=49 discarded)
    const float* xb = x + (size_t)b * (NTOK * CDIM);

    const unsigned short* wq_bf = wbf;            // 576x192
    const unsigned short* wp_bf = wbf + 110592;   // 192x192
    const unsigned short* w1_bf = wbf + 147456;   // 768x192
    const unsigned short* w2_bf = wbf + 294912;   // 192x768

    // ---- mask bitmap (one u64 per row; bits >=49 zero; rows 49..63 zero) ----
    if (tid < 64) {
        unsigned long long m = 0ull;
        if (tid < NTOK) {
            const int* mr = amask + (size_t)b * (NTOK * NTOK) + tid * NTOK;
            for (int j = 0; j < NTOK; ++j)
                m |= (unsigned long long)(mr[j] != 0) << j;
        }
        smask_s[tid] = m;
    }
    // ---- zero vt padding tokens 49..63 (k-dim: must not be NaN garbage) ----
    for (int idx = tid; idx < 32 * 15; idx += 256) {
        int d = idx / 15, t = 49 + (idx - d * 15);
        vt_s[d * VSTR + t] = 0;
    }
    // ---- LN1 (striped rows) ----
    for (int i = w; i < NTOK; i += 4) {
        float v0 = xb[i*CDIM + lane], v1 = xb[i*CDIM + lane + 64], v2 = xb[i*CDIM + lane + 128];
        float s = v0 + v1 + v2, s2 = v0*v0 + v1*v1 + v2*v2;
        #pragma unroll
        for (int off = 32; off > 0; off >>= 1) {
            s += __shfl_xor(s, off, 64); s2 += __shfl_xor(s2, off, 64);
        }
        float m = s * (1.0f/CDIM), vr = s2 * (1.0f/CDIM) - m*m, rs = rsqrtf(vr + 1e-5f);
        xoh[i*XSTR + lane]       = f2bf((v0-m)*rs*g1[lane]     + b1[lane]);
        xoh[i*XSTR + lane + 64]  = f2bf((v1-m)*rs*g1[lane+64]  + b1[lane+64]);
        xoh[i*XSTR + lane + 128] = f2bf((v2-m)*rs*g1[lane+128] + b1[lane+128]);
    }
    __syncthreads();

    // ---- A-fragments of xn (reused across all heads) ----
    bf16x8 axn[6];
    #pragma unroll
    for (int ks = 0; ks < 6; ++ks)
        axn[ks] = *(const bf16x8*)&xoh[arow_c*XSTR + ks*32 + quad*8];

    // ================= attention, per head =================
    for (int h = 0; h < NH; ++h) {
        // ---- qkv: 6 n-tiles (q0 q1 k0 k1 v0 v1), K=192 ----
        #pragma unroll
        for (int nt = 0; nt < 6; ++nt) {
            const int mat = nt >> 1, c16 = nt & 1;
            const int colb = mat*CDIM + h*HD + c16*16;
            f32x4 acc = {0.f, 0.f, 0.f, 0.f};
            #pragma unroll
            for (int ks = 0; ks < 6; ++ks) {
                bf16x8 bw = *(const bf16x8*)&wq_bf[(size_t)(colb + l15)*CDIM + ks*32 + quad*8];
                acc = __builtin_amdgcn_mfma_f32_16x16x32_bf16(axn[ks], bw, acc, 0, 0, 0);
            }
            const float bias = bqkv[colb + l15];
            #pragma unroll
            for (int reg = 0; reg < 4; ++reg) {
                int r = rbase + quad*4 + reg;
                if (r < NTOK) {
                    float val = acc[reg] + bias;
                    int ch = c16*16 + l15;
                    if      (mat == 0) q_s[r*QSTR + ch] = f2bf(val * 0.17677669529663687f);
                    else if (mat == 1) k_s[r*QSTR + ch] = f2bf(val);
                    else               vt_s[ch*VSTR + r] = f2bf(val);
                }
            }
        }
        __syncthreads();

        // ---- scores S[i][j] = q.k  (wave w: rows 16w..16w+15, 4 col-tiles) ----
        bf16x8 aq = *(const bf16x8*)&q_s[arow_c*QSTR + quad*8];
        f32x4 sacc[4];
        #pragma unroll
        for (int nt = 0; nt < 4; ++nt) {
            int krow = nt*16 + l15; krow = (krow < NTOK) ? krow : (NTOK - 1);  // cols >=49 masked
            bf16x8 bk = *(const bf16x8*)&k_s[krow*QSTR + quad*8];
            f32x4 z = {0.f, 0.f, 0.f, 0.f};
            sacc[nt] = __builtin_amdgcn_mfma_f32_16x16x32_bf16(aq, bk, z, 0, 0, 0);
        }
        // ---- softmax in registers (quad-local shuffles), write P bf16 ----
        #pragma unroll
        for (int reg = 0; reg < 4; ++reg) {
            int r = rbase + quad*4 + reg;
            unsigned long long mk = smask_s[r];
            float mx = -INFINITY;
            #pragma unroll
            for (int nt = 0; nt < 4; ++nt) {
                int j = nt*16 + l15;
                float v = ((mk >> j) & 1ull) ? sacc[nt][reg] : -INFINITY;
                mx = fmaxf(mx, v);
            }
            mx = fmaxf(mx, __shfl_xor(mx, 1, 64));
            mx = fmaxf(mx, __shfl_xor(mx, 2, 64));
            mx = fmaxf(mx, __shfl_xor(mx, 4, 64));
            mx = fmaxf(mx, __shfl_xor(mx, 8, 64));
            float e[4]; float sm = 0.f;
            #pragma unroll
            for (int nt = 0; nt < 4; ++nt) {
                int j = nt*16 + l15;
                e[nt] = ((mk >> j) & 1ull) ? __expf(sacc[nt][reg] - mx) : 0.f;
                sm += e[nt];
            }
            sm += __shfl_xor(sm, 1, 64);
            sm += __shfl_xor(sm, 2, 64);
            sm += __shfl_xor(sm, 4, 64);
            sm += __shfl_xor(sm, 8, 64);
            float inv = 1.f / sm;
            if (r < NTOK) {
                #pragma unroll
                for (int nt = 0; nt < 4; ++nt)
                    p_s[r*PSTR + nt*16 + l15] = f2bf(e[nt] * inv);
            }
        }
        // ---- O = P @ V  (k = 64 padded tokens; p rows<49 valid + vt zeros past 48) ----
        bf16x8 ap0 = *(const bf16x8*)&p_s[arow_c*PSTR + quad*8];
        bf16x8 ap1 = *(const bf16x8*)&p_s[arow_c*PSTR + 32 + quad*8];
        #pragma unroll
        for (int nt = 0; nt < 2; ++nt) {
            bf16x8 bv0 = *(const bf16x8*)&vt_s[(nt*16 + l15)*VSTR + quad*8];
            bf16x8 bv1 = *(const bf16x8*)&vt_s[(nt*16 + l15)*VSTR + 32 + quad*8];
            f32x4 oa = {0.f, 0.f, 0.f, 0.f};
            oa = __builtin_amdgcn_mfma_f32_16x16x32_bf16(ap0, bv0, oa, 0, 0, 0);
            oa = __builtin_amdgcn_mfma_f32_16x16x32_bf16(ap1, bv1, oa, 0, 0, 0);
            #pragma unroll
            for (int reg = 0; reg < 4; ++reg) {
                int r = rbase + quad*4 + reg;
                if (r < NTOK) xoh[r*XSTR + h*HD + nt*16 + l15] = f2bf(oa[reg]);
            }
        }
        __syncthreads();
    }

    // ================= proj: ap = O @ wproj^T + bproj (bf16) =================
    {
        bf16x8 ao[6];
        #pragma unroll
        for (int ks = 0; ks < 6; ++ks)
            ao[ks] = *(const bf16x8*)&xoh[arow_c*XSTR + ks*32 + quad*8];
        #pragma unroll
        for (int nt = 0; nt < 12; ++nt) {
            f32x4 pa = {0.f, 0.f, 0.f, 0.f};
            #pragma unroll
            for (int ks = 0; ks < 6; ++ks) {
                bf16x8 bw = *(const bf16x8*)&wp_bf[(size_t)(nt*16 + l15)*CDIM + ks*32 + quad*8];
                pa = __builtin_amdgcn_mfma_f32_16x16x32_bf16(ao[ks], bw, pa, 0, 0, 0);
            }
            float bias = bpr[nt*16 + l15];
            #pragma unroll
            for (int reg = 0; reg < 4; ++reg) {
                int r = rbase + quad*4 + reg;
                if (r < NTOK) ap_s[r*XSTR + nt*16 + l15] = f2bf(pa[reg] + bias);
            }
        }
    }
    __syncthreads();

    // ================= LN2: x1 = x + ap, normalize -> xoh =================
    for (int i = w; i < NTOK; i += 4) {
        float v0 = xb[i*CDIM + lane]       + bfu2f((unsigned short)ap_s[i*XSTR + lane]);
        float v1 = xb[i*CDIM + lane + 64]  + bfu2f((unsigned short)ap_s[i*XSTR + lane + 64]);
        float v2 = xb[i*CDIM + lane + 128] + bfu2f((unsigned short)ap_s[i*XSTR + lane + 128]);
        float s = v0 + v1 + v2, s2 = v0*v0 + v1*v1 + v2*v2;
        #pragma unroll
        for (int off = 32; off > 0; off >>= 1) {
            s += __shfl_xor(s, off, 64); s2 += __shfl_xor(s2, off, 64);
        }
        float m = s * (1.0f/CDIM), vr = s2 * (1.0f/CDIM) - m*m, rs = rsqrtf(vr + 1e-5f);
        xoh[i*XSTR + lane]       = f2bf((v0-m)*rs*g2[lane]     + b2[lane]);
        xoh[i*XSTR + lane + 64]  = f2bf((v1-m)*rs*g2[lane+64]  + b2[lane+64]);
        xoh[i*XSTR + lane + 128] = f2bf((v2-m)*rs*g2[lane+128] + b2[lane+128]);
    }
    __syncthreads();

    // ================= MLP: 4 hidden chunks of 192, fc2 acc in regs =================
    {
        bf16x8 ax[6];
        #pragma unroll
        for (int ks = 0; ks < 6; ++ks)
            ax[ks] = *(const bf16x8*)&xoh[arow_c*XSTR + ks*32 + quad*8];
        f32x4 facc2[12];
        #pragma unroll
        for (int nt = 0; nt < 12; ++nt) facc2[nt] = (f32x4){0.f, 0.f, 0.f, 0.f};

        for (int jc = 0; jc < 4; ++jc) {
            // fc1 chunk + gelu -> hm (xoh reuse; rows of this wave only)
            #pragma unroll
            for (int nt2 = 0; nt2 < 12; ++nt2) {
                f32x4 fa = {0.f, 0.f, 0.f, 0.f};
                const int hc = jc*CDIM + nt2*16 + l15;
                #pragma unroll
                for (int ks = 0; ks < 6; ++ks) {
                    bf16x8 bw = *(const bf16x8*)&w1_bf[(size_t)hc*CDIM + ks*32 + quad*8];
                    fa = __builtin_amdgcn_mfma_f32_16x16x32_bf16(ax[ks], bw, fa, 0, 0, 0);
                }
                const float bias = bf1[hc];
                #pragma unroll
                for (int reg = 0; reg < 4; ++reg) {
                    int r = rbase + quad*4 + reg;
                    if (r < NTOK) {
                        float v = fa[reg] + bias;
                        float g = 0.5f * v * (1.0f + erff(v * 0.70710678118654752f));
                        xoh[r*XSTR + nt2*16 + l15] = f2bf(g);
                    }
                }
            }
            // fc2 partial (K = this chunk), accumulate in regs
            bf16x8 ah[6];
            #pragma unroll
            for (int ks = 0; ks < 6; ++ks)
                ah[ks] = *(const bf16x8*)&xoh[arow_c*XSTR + ks*32 + quad*8];
            #pragma unroll
            for (int nt = 0; nt < 12; ++nt) {
                #pragma unroll
                for (int ks = 0; ks < 6; ++ks) {
                    bf16x8 bw = *(const bf16x8*)&w2_bf[(size_t)(nt*16 + l15)*768 + jc*CDIM + ks*32 + quad*8];
                    facc2[nt] = __builtin_amdgcn_mfma_f32_16x16x32_bf16(ah[ks], bw, facc2[nt], 0, 0, 0);
                }
            }
        }
        // ---- final: out = x + ap + mlp + b_fc2 ----
        float* ob = out + (size_t)b * (NTOK * CDIM);
        #pragma unroll
        for (int nt = 0; nt < 12; ++nt) {
            const int col = nt*16 + l15;
            const float bias = bf2[col];
            #pragma unroll
            for (int reg = 0; reg < 4; ++reg) {
                int r = rbase + quad*4 + reg;
                if (r < NTOK)
                    ob[r*CDIM + col] = facc2[nt][reg] + bias + xb[r*CDIM + col]
                                     + bfu2f((unsigned short)ap_s[r*XSTR + col]);
            }
        }
    }
}

extern "C" void kernel_launch(void* const* d_in, const int* in_sizes, int n_in,
                              void* d_out, int out_size, void* d_ws, size_t ws_size,
                              hipStream_t stream) {
    (void)in_sizes; (void)n_in; (void)out_size; (void)ws_size;
    const float* x    = (const float*)d_in[0];
    const int*   am   = (const int*)d_in[1];
    const float* g1   = (const float*)d_in[2];
    const float* b1   = (const float*)d_in[3];
    const float* wqkv = (const float*)d_in[4];
    const float* bqkv = (const float*)d_in[5];
    const float* wpr  = (const float*)d_in[6];
    const float* bpr  = (const float*)d_in[7];
    const float* g2   = (const float*)d_in[8];
    const float* b2   = (const float*)d_in[9];
    const float* wf1  = (const float*)d_in[10];
    const float* bf1  = (const float*)d_in[11];
    const float* wf2  = (const float*)d_in[12];
    const float* bf2  = (const float*)d_in[13];
    unsigned short* wbf = (unsigned short*)d_ws;

    conv_weights<<<432, 256, 0, stream>>>(wqkv, wpr, wf1, wf2, wbf);
    swin_mfma_kernel<<<4096, 256, 0, stream>>>(
        x, am, g1, b1, bqkv, bpr, g2, b2, bf1, bf2, wbf, (float*)d_out);
}